// Round 1
// baseline (244.083 us; speedup 1.0000x reference)
//
#include <hip/hip_runtime.h>
#include <hip/hip_bf16.h>
#include <cstdint>

#define NHEADS 8
#define NPOINTS 4

// ---------------------------------------------------------------------------
// Tiled fp32 GEMM with bias: C[M,N] = A[M,K] @ B[K,N] + bias[N]
// Row-major everywhere. Requires M%64==0, N%64==0, K%16==0.
// 64x64 tile per block, 256 threads, 4x4 micro-tile per thread, BK=16.
// ---------------------------------------------------------------------------
__global__ __launch_bounds__(256) void gemm_bias_f32(
    const float* __restrict__ A, const float* __restrict__ B,
    const float* __restrict__ bias, float* __restrict__ C,
    int M, int N, int K)
{
  __shared__ float As[16][68];  // [k][row], 68 = 64+4 pad keeps 16B align, breaks bank stride
  __shared__ float Bs[16][68];  // [k][col]
  const int tid  = threadIdx.x;
  const int tx   = tid & 15;
  const int ty   = tid >> 4;
  const int brow = blockIdx.y * 64;
  const int bcol = blockIdx.x * 64;

  const int arow  = tid >> 2;        // 0..63
  const int acol4 = (tid & 3) << 2;  // 0,4,8,12
  const int bkrow = tid >> 4;        // 0..15
  const int bcol4 = (tid & 15) << 2; // 0..60

  float acc[4][4] = {};

  for (int k0 = 0; k0 < K; k0 += 16) {
    float4 av = *(const float4*)&A[(size_t)(brow + arow) * K + (k0 + acol4)];
    float4 bv = *(const float4*)&B[(size_t)(k0 + bkrow) * N + (bcol + bcol4)];
    __syncthreads();  // previous iteration's LDS reads must be done
    As[acol4 + 0][arow] = av.x;
    As[acol4 + 1][arow] = av.y;
    As[acol4 + 2][arow] = av.z;
    As[acol4 + 3][arow] = av.w;
    *(float4*)&Bs[bkrow][bcol4] = bv;
    __syncthreads();
#pragma unroll
    for (int kk = 0; kk < 16; ++kk) {
      float4 a4 = *(const float4*)&As[kk][ty << 2];
      float4 b4 = *(const float4*)&Bs[kk][tx << 2];
      float a[4] = {a4.x, a4.y, a4.z, a4.w};
      float b[4] = {b4.x, b4.y, b4.z, b4.w};
#pragma unroll
      for (int i = 0; i < 4; ++i)
#pragma unroll
        for (int j = 0; j < 4; ++j)
          acc[i][j] += a[i] * b[j];
    }
  }

  float4 bias4 = *(const float4*)&bias[bcol + (tx << 2)];
#pragma unroll
  for (int i = 0; i < 4; ++i) {
    float4 v;
    v.x = acc[i][0] + bias4.x;
    v.y = acc[i][1] + bias4.y;
    v.z = acc[i][2] + bias4.z;
    v.w = acc[i][3] + bias4.w;
    *(float4*)&C[(size_t)(brow + (ty << 2) + i) * N + bcol + (tx << 2)] = v;
  }
}

// ---------------------------------------------------------------------------
// Offsets + attention-logits projection.
// Each block handles 8 query rows. offs[bq,64] = q @ W_off + b_off,
// logits[bq,32] = q @ W_attn + b_attn.  (softmax is done in sample_kernel)
// ---------------------------------------------------------------------------
__global__ __launch_bounds__(128) void proj_kernel(
    const float* __restrict__ query,
    const float* __restrict__ W_off, const float* __restrict__ b_off,
    const float* __restrict__ W_attn, const float* __restrict__ b_attn,
    float* __restrict__ offs, float* __restrict__ logits)
{
  __shared__ float q_lds[8][256];
  const int row0 = blockIdx.x * 8;
  const int tid  = threadIdx.x;

  for (int i = tid; i < 512; i += 128) {      // 8 rows * 64 float4
    const int r  = i >> 6;
    const int c4 = (i & 63) << 2;
    *(float4*)&q_lds[r][c4] = *(const float4*)&query[(size_t)(row0 + r) * 256 + c4];
  }
  __syncthreads();
  if (tid >= 96) return;

  float acc[8] = {};
  if (tid < 64) {
    for (int k4 = 0; k4 < 256; k4 += 4) {
      const float w0 = W_off[(k4 + 0) * 64 + tid];
      const float w1 = W_off[(k4 + 1) * 64 + tid];
      const float w2 = W_off[(k4 + 2) * 64 + tid];
      const float w3 = W_off[(k4 + 3) * 64 + tid];
#pragma unroll
      for (int r = 0; r < 8; ++r) {
        float4 q4 = *(const float4*)&q_lds[r][k4];
        acc[r] += q4.x * w0 + q4.y * w1 + q4.z * w2 + q4.w * w3;
      }
    }
    const float bb = b_off[tid];
#pragma unroll
    for (int r = 0; r < 8; ++r)
      offs[(size_t)(row0 + r) * 64 + tid] = acc[r] + bb;
  } else {
    const int j = tid - 64;
    for (int k4 = 0; k4 < 256; k4 += 4) {
      const float w0 = W_attn[(k4 + 0) * 32 + j];
      const float w1 = W_attn[(k4 + 1) * 32 + j];
      const float w2 = W_attn[(k4 + 2) * 32 + j];
      const float w3 = W_attn[(k4 + 3) * 32 + j];
#pragma unroll
      for (int r = 0; r < 8; ++r) {
        float4 q4 = *(const float4*)&q_lds[r][k4];
        acc[r] += q4.x * w0 + q4.y * w1 + q4.z * w2 + q4.w * w3;
      }
    }
    const float bb = b_attn[j];
#pragma unroll
    for (int r = 0; r < 8; ++r)
      logits[(size_t)(row0 + r) * 32 + j] = acc[r] + bb;
  }
}

// ---------------------------------------------------------------------------
// Softmax + bilinear sampling + weighted accumulation.
// One block per (b,q). 256 threads: tid = head*32 + dh  (== channel in [0,256)).
// mid[bq, tid] = sum_p softmax(logits)[h,p] * bilinear(values[b], loc[h,p])[ch]
// ---------------------------------------------------------------------------
__global__ __launch_bounds__(256) void sample_kernel(
    const float* __restrict__ refp,    // [BQ,2]
    const float* __restrict__ offs,    // [BQ,64]  (h*8 + p*2 + c)
    const float* __restrict__ logits,  // [BQ,32]  (h*4 + p)
    const float* __restrict__ values,  // [B,HW,256]
    float* __restrict__ mid,           // [BQ,256]
    const int* __restrict__ hptr, const int* __restrict__ wptr,
    int Q, int HW)
{
  const int bq  = blockIdx.x;
  const int b   = bq / Q;
  const int tid = threadIdx.x;

  __shared__ float off_s[64];
  __shared__ float lg_s[32];
  __shared__ float wt_s[32];
  __shared__ float ref_s[2];

  if (tid < 64) {
    off_s[tid] = offs[(size_t)bq * 64 + tid];
  } else if (tid < 96) {
    lg_s[tid - 64] = logits[(size_t)bq * 32 + (tid - 64)];
  } else if (tid == 96) {
    ref_s[0] = refp[(size_t)bq * 2 + 0];
    ref_s[1] = refp[(size_t)bq * 2 + 1];
  }
  __syncthreads();
  if (tid < 8) {  // per-head softmax over 4 points
    const float l0 = lg_s[tid * 4 + 0], l1 = lg_s[tid * 4 + 1];
    const float l2 = lg_s[tid * 4 + 2], l3 = lg_s[tid * 4 + 3];
    const float m  = fmaxf(fmaxf(l0, l1), fmaxf(l2, l3));
    const float e0 = expf(l0 - m), e1 = expf(l1 - m);
    const float e2 = expf(l2 - m), e3 = expf(l3 - m);
    const float inv = 1.0f / (e0 + e1 + e2 + e3);
    wt_s[tid * 4 + 0] = e0 * inv;
    wt_s[tid * 4 + 1] = e1 * inv;
    wt_s[tid * 4 + 2] = e2 * inv;
    wt_s[tid * 4 + 3] = e3 * inv;
  }
  __syncthreads();

  const int W_ = *wptr;
  const int H_ = *hptr;
  const int hh = tid >> 5;
  const float rx = ref_s[0], ry = ref_s[1];
  const float* vb = values + (size_t)b * HW * 256;

  float acc = 0.0f;
#pragma unroll
  for (int p = 0; p < NPOINTS; ++p) {
    float lx = rx + off_s[hh * 8 + p * 2 + 0];
    float ly = ry + off_s[hh * 8 + p * 2 + 1];
    lx = fminf(fmaxf(lx, 0.0f), 1.0f);
    ly = fminf(fmaxf(ly, 0.0f), 1.0f);
    const float sx = lx * (float)(W_ - 1);
    const float sy = ly * (float)(H_ - 1);
    int x0 = (int)floorf(sx);
    int y0 = (int)floorf(sy);
    x0 = min(max(x0, 0), W_ - 1);
    y0 = min(max(y0, 0), H_ - 1);
    const int x1 = min(x0 + 1, W_ - 1);
    const int y1 = min(y0 + 1, H_ - 1);
    const float wx1 = sx - (float)x0, wx0 = 1.0f - wx1;
    const float wy1 = sy - (float)y0, wy0 = 1.0f - wy1;

    const float* r0 = vb + (size_t)(y0 * W_) * 256 + tid;
    const float* r1 = vb + (size_t)(y1 * W_) * 256 + tid;
    const float g00 = r0[(size_t)x0 * 256];
    const float g10 = r0[(size_t)x1 * 256];
    const float g01 = r1[(size_t)x0 * 256];
    const float g11 = r1[(size_t)x1 * 256];

    const float bl = g00 * (wx0 * wy0) + g01 * (wx0 * wy1)
                   + g10 * (wx1 * wy0) + g11 * (wx1 * wy1);
    acc += wt_s[hh * 4 + p] * bl;
  }
  mid[(size_t)bq * 256 + tid] = acc;
}

// ---------------------------------------------------------------------------
extern "C" void kernel_launch(void* const* d_in, const int* in_sizes, int n_in,
                              void* d_out, int out_size, void* d_ws, size_t ws_size,
                              hipStream_t stream)
{
  const float* query   = (const float*)d_in[0];
  const float* refp    = (const float*)d_in[1];
  const float* input_f = (const float*)d_in[2];
  const int*   hptr    = (const int*)d_in[3];
  const int*   wptr    = (const int*)d_in[4];
  const float* W_off   = (const float*)d_in[5];
  const float* b_off   = (const float*)d_in[6];
  const float* W_attn  = (const float*)d_in[7];
  const float* b_attn  = (const float*)d_in[8];
  const float* W_val   = (const float*)d_in[9];
  const float* b_val   = (const float*)d_in[10];
  const float* W_out   = (const float*)d_in[11];
  const float* b_out   = (const float*)d_in[12];
  float* out = (float*)d_out;

  const int D   = 256;
  const int BQ  = in_sizes[0] / D;   // 8*2048 = 16384
  const int B   = 8;                 // fixed problem shape
  const int Q   = BQ / B;            // 2048
  const int BHW = in_sizes[2] / D;   // 8*10000 = 80000
  const int HW  = BHW / B;           // 10000

  char* ws = (char*)d_ws;
  float* values = (float*)ws;                                   // BHW*256 f32 = 81.92 MB
  size_t o = (size_t)BHW * D * sizeof(float);
  float* offsb  = (float*)(ws + o);  o += (size_t)BQ * 64 * sizeof(float);
  float* logitb = (float*)(ws + o);  o += (size_t)BQ * 32 * sizeof(float);
  float* mid    = (float*)(ws + o);  // BQ*256 f32

  // 1. values = input_flatten @ W_val + b_val      [80000,256]@[256,256]
  gemm_bias_f32<<<dim3(D / 64, BHW / 64), 256, 0, stream>>>(
      input_f, W_val, b_val, values, BHW, D, D);

  // 2. offsets + attention logits                  [16384,256]@[256,96]
  proj_kernel<<<BQ / 8, 128, 0, stream>>>(
      query, W_off, b_off, W_attn, b_attn, offsb, logitb);

  // 3. softmax + bilinear sampling                 -> mid [16384,256]
  sample_kernel<<<BQ, 256, 0, stream>>>(
      refp, offsb, logitb, values, mid, hptr, wptr, Q, HW);

  // 4. out = mid @ W_out + b_out                   [16384,256]@[256,256]
  gemm_bias_f32<<<dim3(D / 64, BQ / 64), 256, 0, stream>>>(
      mid, W_out, b_out, out, BQ, D, D);
}

// Round 2
// 214.604 us; speedup vs baseline: 1.1374x; 1.1374x over previous
//
#include <hip/hip_runtime.h>
#include <hip/hip_bf16.h>
#include <cstdint>

#define NHEADS 8
#define NPOINTS 4

typedef __bf16 bf16x8 __attribute__((ext_vector_type(8)));
typedef float f32x4 __attribute__((ext_vector_type(4)));

__device__ __forceinline__ ushort f2bf_rn(float x) {
  union { float f; uint32_t u; } c; c.f = x;
  uint32_t r = c.u + 0x7fffu + ((c.u >> 16) & 1u);
  return (ushort)(r >> 16);
}
__device__ __forceinline__ float bf2f(ushort h) {
  union { uint32_t u; float f; } c; c.u = ((uint32_t)h) << 16; return c.f;
}

// XOR-swizzled LDS index (ushort units). Tile row = 64 bf16 = 128 B.
// byte ^= (row&7)<<4 spreads the 16B column slots across banks (G4 pattern).
__device__ __forceinline__ int swz_idx(int row, int byte_in_row) {
  return ((row * 128 + byte_in_row) ^ ((row & 7) << 4)) >> 1;
}

// ---------------------------------------------------------------------------
// Split-bf16 (3x MFMA) GEMM with bias: C[M,N] = A[M,K] @ B[K,N] + bias[N]
// A fp32 row-major (converted to hi/lo bf16 on the fly).
// B pre-split+transposed: BT_hi/BT_lo are bf16 [N][K] row-major.
// Tile 128x128, BK=64, 256 threads (4 waves, each 64x64 via 4x4 frags of
// 16x16x32 MFMA). Requires M%128==0, N%128==0, K%64==0.
// Accuracy: hi*hi + hi*lo + lo*hi — error ~2^-16 relative (near-fp32).
// ---------------------------------------------------------------------------
__global__ __launch_bounds__(256, 2) void gemm_split3(
    const float* __restrict__ A,
    const ushort* __restrict__ BT_hi, const ushort* __restrict__ BT_lo,
    const float* __restrict__ bias, float* __restrict__ C,
    int M, int N, int K)
{
  __shared__ ushort Ah[128 * 64], Al[128 * 64], Bh[128 * 64], Bl[128 * 64];
  const int tid  = threadIdx.x;
  const int lane = tid & 63, wave = tid >> 6;
  const int wm = (wave >> 1) * 64, wn = (wave & 1) * 64;
  const int lrow = lane & 15, lgrp = lane >> 4;
  const long brow = (long)blockIdx.y * 128;
  const int  bcol = blockIdx.x * 128;

  f32x4 acc[4][4] = {};

  for (int k0 = 0; k0 < K; k0 += 64) {
    // ---- global loads to regs ----
    float4 areg[8];
#pragma unroll
    for (int i = 0; i < 8; ++i) {
      const int idx = i * 256 + tid;
      const int r = idx >> 4, c = (idx & 15) << 2;       // 16 float4 per row
      areg[i] = *(const float4*)&A[(size_t)(brow + r) * K + k0 + c];
    }
    uint4 bhreg[4], blreg[4];
#pragma unroll
    for (int i = 0; i < 4; ++i) {
      const int idx = i * 256 + tid;
      const int r = idx >> 3, c = (idx & 7) << 3;        // 8 x (8 bf16) per row
      bhreg[i] = *(const uint4*)&BT_hi[(size_t)(bcol + r) * K + k0 + c];
      blreg[i] = *(const uint4*)&BT_lo[(size_t)(bcol + r) * K + k0 + c];
    }

    __syncthreads();  // previous iteration's LDS reads must be complete

    // ---- convert + LDS writes (swizzled) ----
#pragma unroll
    for (int i = 0; i < 8; ++i) {
      const int idx = i * 256 + tid;
      const int r = idx >> 4, c = (idx & 15) << 2;
      const float v[4] = {areg[i].x, areg[i].y, areg[i].z, areg[i].w};
      ushort hi[4], lo[4];
#pragma unroll
      for (int j = 0; j < 4; ++j) {
        hi[j] = f2bf_rn(v[j]);
        lo[j] = f2bf_rn(v[j] - bf2f(hi[j]));
      }
      const int si = swz_idx(r, c * 2);
      *(ushort4*)&Ah[si] = make_ushort4(hi[0], hi[1], hi[2], hi[3]);
      *(ushort4*)&Al[si] = make_ushort4(lo[0], lo[1], lo[2], lo[3]);
    }
#pragma unroll
    for (int i = 0; i < 4; ++i) {
      const int idx = i * 256 + tid;
      const int r = idx >> 3, c = (idx & 7) << 3;
      const int si = swz_idx(r, c * 2);
      *(uint4*)&Bh[si] = bhreg[i];
      *(uint4*)&Bl[si] = blreg[i];
    }

    __syncthreads();

    // ---- fragment reads + MFMA ----
#pragma unroll
    for (int s = 0; s < 2; ++s) {   // two K=32 steps per BK=64
      bf16x8 ah[4], al[4], bh[4], bl[4];
#pragma unroll
      for (int t = 0; t < 4; ++t) {
        const int ar = wm + t * 16 + lrow;
        const int ai = swz_idx(ar, s * 64 + lgrp * 16);
        ah[t] = *(const bf16x8*)&Ah[ai];
        al[t] = *(const bf16x8*)&Al[ai];
        const int br_ = wn + t * 16 + lrow;
        const int bi = swz_idx(br_, s * 64 + lgrp * 16);
        bh[t] = *(const bf16x8*)&Bh[bi];
        bl[t] = *(const bf16x8*)&Bl[bi];
      }
#pragma unroll
      for (int mt = 0; mt < 4; ++mt)
#pragma unroll
        for (int nt = 0; nt < 4; ++nt) {
          acc[mt][nt] = __builtin_amdgcn_mfma_f32_16x16x32_bf16(ah[mt], bh[nt], acc[mt][nt], 0, 0, 0);
          acc[mt][nt] = __builtin_amdgcn_mfma_f32_16x16x32_bf16(ah[mt], bl[nt], acc[mt][nt], 0, 0, 0);
          acc[mt][nt] = __builtin_amdgcn_mfma_f32_16x16x32_bf16(al[mt], bh[nt], acc[mt][nt], 0, 0, 0);
        }
    }
  }

  // ---- epilogue: C/D layout col=lane&15, row=(lane>>4)*4+reg ----
#pragma unroll
  for (int nt = 0; nt < 4; ++nt) {
    const int col = bcol + wn + nt * 16 + lrow;
    const float bb = bias[col];
#pragma unroll
    for (int mt = 0; mt < 4; ++mt) {
      const long row0 = brow + wm + mt * 16 + lgrp * 4;
      const f32x4 v = acc[mt][nt];
#pragma unroll
      for (int j = 0; j < 4; ++j)
        C[(size_t)(row0 + j) * N + col] = v[j] + bb;
    }
  }
}

// ---------------------------------------------------------------------------
// Weight prep: W fp32 [256][256] -> WT_hi/WT_lo bf16 [n][k] (transposed+split)
// ---------------------------------------------------------------------------
__global__ __launch_bounds__(256) void prep_wt(
    const float* __restrict__ W, ushort* __restrict__ WT_hi, ushort* __restrict__ WT_lo)
{
  const int n = blockIdx.x;
  const int k = threadIdx.x;
  const float w = W[k * 256 + n];
  const ushort hi = f2bf_rn(w);
  const ushort lo = f2bf_rn(w - bf2f(hi));
  WT_hi[n * 256 + k] = hi;
  WT_lo[n * 256 + k] = lo;
}

// ---------------------------------------------------------------------------
// Offsets + attention-logits projection (unchanged from round 0).
// ---------------------------------------------------------------------------
__global__ __launch_bounds__(128) void proj_kernel(
    const float* __restrict__ query,
    const float* __restrict__ W_off, const float* __restrict__ b_off,
    const float* __restrict__ W_attn, const float* __restrict__ b_attn,
    float* __restrict__ offs, float* __restrict__ logits)
{
  __shared__ float q_lds[8][256];
  const int row0 = blockIdx.x * 8;
  const int tid  = threadIdx.x;

  for (int i = tid; i < 512; i += 128) {
    const int r  = i >> 6;
    const int c4 = (i & 63) << 2;
    *(float4*)&q_lds[r][c4] = *(const float4*)&query[(size_t)(row0 + r) * 256 + c4];
  }
  __syncthreads();
  if (tid >= 96) return;

  float acc[8] = {};
  if (tid < 64) {
    for (int k4 = 0; k4 < 256; k4 += 4) {
      const float w0 = W_off[(k4 + 0) * 64 + tid];
      const float w1 = W_off[(k4 + 1) * 64 + tid];
      const float w2 = W_off[(k4 + 2) * 64 + tid];
      const float w3 = W_off[(k4 + 3) * 64 + tid];
#pragma unroll
      for (int r = 0; r < 8; ++r) {
        float4 q4 = *(const float4*)&q_lds[r][k4];
        acc[r] += q4.x * w0 + q4.y * w1 + q4.z * w2 + q4.w * w3;
      }
    }
    const float bb = b_off[tid];
#pragma unroll
    for (int r = 0; r < 8; ++r)
      offs[(size_t)(row0 + r) * 64 + tid] = acc[r] + bb;
  } else {
    const int j = tid - 64;
    for (int k4 = 0; k4 < 256; k4 += 4) {
      const float w0 = W_attn[(k4 + 0) * 32 + j];
      const float w1 = W_attn[(k4 + 1) * 32 + j];
      const float w2 = W_attn[(k4 + 2) * 32 + j];
      const float w3 = W_attn[(k4 + 3) * 32 + j];
#pragma unroll
      for (int r = 0; r < 8; ++r) {
        float4 q4 = *(const float4*)&q_lds[r][k4];
        acc[r] += q4.x * w0 + q4.y * w1 + q4.z * w2 + q4.w * w3;
      }
    }
    const float bb = b_attn[j];
#pragma unroll
    for (int r = 0; r < 8; ++r)
      logits[(size_t)(row0 + r) * 32 + j] = acc[r] + bb;
  }
}

// ---------------------------------------------------------------------------
// Softmax + bilinear sampling + weighted accumulation (unchanged).
// ---------------------------------------------------------------------------
__global__ __launch_bounds__(256) void sample_kernel(
    const float* __restrict__ refp,
    const float* __restrict__ offs,
    const float* __restrict__ logits,
    const float* __restrict__ values,
    float* __restrict__ mid,
    const int* __restrict__ hptr, const int* __restrict__ wptr,
    int Q, int HW)
{
  const int bq  = blockIdx.x;
  const int b   = bq / Q;
  const int tid = threadIdx.x;

  __shared__ float off_s[64];
  __shared__ float lg_s[32];
  __shared__ float wt_s[32];
  __shared__ float ref_s[2];

  if (tid < 64) {
    off_s[tid] = offs[(size_t)bq * 64 + tid];
  } else if (tid < 96) {
    lg_s[tid - 64] = logits[(size_t)bq * 32 + (tid - 64)];
  } else if (tid == 96) {
    ref_s[0] = refp[(size_t)bq * 2 + 0];
    ref_s[1] = refp[(size_t)bq * 2 + 1];
  }
  __syncthreads();
  if (tid < 8) {
    const float l0 = lg_s[tid * 4 + 0], l1 = lg_s[tid * 4 + 1];
    const float l2 = lg_s[tid * 4 + 2], l3 = lg_s[tid * 4 + 3];
    const float m  = fmaxf(fmaxf(l0, l1), fmaxf(l2, l3));
    const float e0 = expf(l0 - m), e1 = expf(l1 - m);
    const float e2 = expf(l2 - m), e3 = expf(l3 - m);
    const float inv = 1.0f / (e0 + e1 + e2 + e3);
    wt_s[tid * 4 + 0] = e0 * inv;
    wt_s[tid * 4 + 1] = e1 * inv;
    wt_s[tid * 4 + 2] = e2 * inv;
    wt_s[tid * 4 + 3] = e3 * inv;
  }
  __syncthreads();

  const int W_ = *wptr;
  const int H_ = *hptr;
  const int hh = tid >> 5;
  const float rx = ref_s[0], ry = ref_s[1];
  const float* vb = values + (size_t)b * HW * 256;

  float acc = 0.0f;
#pragma unroll
  for (int p = 0; p < NPOINTS; ++p) {
    float lx = rx + off_s[hh * 8 + p * 2 + 0];
    float ly = ry + off_s[hh * 8 + p * 2 + 1];
    lx = fminf(fmaxf(lx, 0.0f), 1.0f);
    ly = fminf(fmaxf(ly, 0.0f), 1.0f);
    const float sx = lx * (float)(W_ - 1);
    const float sy = ly * (float)(H_ - 1);
    int x0 = (int)floorf(sx);
    int y0 = (int)floorf(sy);
    x0 = min(max(x0, 0), W_ - 1);
    y0 = min(max(y0, 0), H_ - 1);
    const int x1 = min(x0 + 1, W_ - 1);
    const int y1 = min(y0 + 1, H_ - 1);
    const float wx1 = sx - (float)x0, wx0 = 1.0f - wx1;
    const float wy1 = sy - (float)y0, wy0 = 1.0f - wy1;

    const float* r0 = vb + (size_t)(y0 * W_) * 256 + tid;
    const float* r1 = vb + (size_t)(y1 * W_) * 256 + tid;
    const float g00 = r0[(size_t)x0 * 256];
    const float g10 = r0[(size_t)x1 * 256];
    const float g01 = r1[(size_t)x0 * 256];
    const float g11 = r1[(size_t)x1 * 256];

    const float bl = g00 * (wx0 * wy0) + g01 * (wx0 * wy1)
                   + g10 * (wx1 * wy0) + g11 * (wx1 * wy1);
    acc += wt_s[hh * 4 + p] * bl;
  }
  mid[(size_t)bq * 256 + tid] = acc;
}

// ---------------------------------------------------------------------------
extern "C" void kernel_launch(void* const* d_in, const int* in_sizes, int n_in,
                              void* d_out, int out_size, void* d_ws, size_t ws_size,
                              hipStream_t stream)
{
  const float* query   = (const float*)d_in[0];
  const float* refp    = (const float*)d_in[1];
  const float* input_f = (const float*)d_in[2];
  const int*   hptr    = (const int*)d_in[3];
  const int*   wptr    = (const int*)d_in[4];
  const float* W_off   = (const float*)d_in[5];
  const float* b_off   = (const float*)d_in[6];
  const float* W_attn  = (const float*)d_in[7];
  const float* b_attn  = (const float*)d_in[8];
  const float* W_val   = (const float*)d_in[9];
  const float* b_val   = (const float*)d_in[10];
  const float* W_out   = (const float*)d_in[11];
  const float* b_out   = (const float*)d_in[12];
  float* out = (float*)d_out;

  const int D   = 256;
  const int BQ  = in_sizes[0] / D;   // 16384
  const int B   = 8;
  const int Q   = BQ / B;            // 2048
  const int BHW = in_sizes[2] / D;   // 80000
  const int HW  = BHW / B;           // 10000

  char* ws = (char*)d_ws;
  float* values = (float*)ws;                                   // 81.92 MB
  size_t o = (size_t)BHW * D * sizeof(float);
  float* offsb  = (float*)(ws + o);  o += (size_t)BQ * 64 * sizeof(float);  // 4.19 MB
  float* logitb = (float*)(ws + o);  o += (size_t)BQ * 32 * sizeof(float);  // 2.10 MB
  float* mid    = (float*)(ws + o);                             // 16.78 MB

  // Overlay split-weight buffers on dead regions (no extra ws vs round 0):
  //  - WvT (512 KB) sits at head of `mid` (mid is written only later, in sample;
  //    WvT is dead after gemm1).
  //  - WoT (512 KB) sits at head of `offs` (offs is dead after sample; WoT is
  //    written after sample, used in gemm2).
  ushort* WvT_hi = (ushort*)mid;
  ushort* WvT_lo = WvT_hi + 256 * 256;
  ushort* WoT_hi = (ushort*)offsb;
  ushort* WoT_lo = WoT_hi + 256 * 256;

  // 1. split/transpose W_val, then values = input_flatten @ W_val + b_val
  prep_wt<<<256, 256, 0, stream>>>(W_val, WvT_hi, WvT_lo);
  gemm_split3<<<dim3(D / 128, BHW / 128), 256, 0, stream>>>(
      input_f, WvT_hi, WvT_lo, b_val, values, BHW, D, D);

  // 2. offsets + attention logits
  proj_kernel<<<BQ / 8, 128, 0, stream>>>(
      query, W_off, b_off, W_attn, b_attn, offsb, logitb);

  // 3. softmax + bilinear sampling -> mid
  sample_kernel<<<BQ, 256, 0, stream>>>(
      refp, offsb, logitb, values, mid, hptr, wptr, Q, HW);

  // 4. split/transpose W_out, then out = mid @ W_out + b_out
  prep_wt<<<256, 256, 0, stream>>>(W_out, WoT_hi, WoT_lo);
  gemm_split3<<<dim3(D / 128, BQ / 128), 256, 0, stream>>>(
      mid, WoT_hi, WoT_lo, b_out, out, BQ, D, D);
}